// Round 6
// baseline (237.945 us; speedup 1.0000x reference)
//
#include <hip/hip_runtime.h>

typedef __bf16 bf16_t;
typedef bf16_t bf16x8 __attribute__((ext_vector_type(8)));
typedef bf16_t bf16x4 __attribute__((ext_vector_type(4)));
typedef float  f32x4  __attribute__((ext_vector_type(4)));
typedef float  f32x16 __attribute__((ext_vector_type(16)));
typedef unsigned int u32;
typedef u32 u32x2 __attribute__((ext_vector_type(2)));
typedef u32 u32x4 __attribute__((ext_vector_type(4)));

#define T_SEQ 2048
#define C_DIM 1024
#define NH    16
#define DH    64
#define BATCH 4
#define M_TOK (BATCH * T_SEQ)   // 8192

// Q pre-scale: 1/sqrt(64) * log2(e)  -> softmax computed in exp2 domain
#define Q_SCALE 0.1803368801111137f
#define DEFER_THR 8.0f

#define AS1 __attribute__((address_space(1)))
#define AS3 __attribute__((address_space(3)))

__device__ __forceinline__ void gld_lds16(const bf16_t* g, bf16_t* l) {
  __builtin_amdgcn_global_load_lds(
      (const AS1 u32*)(uintptr_t)g,
      (AS3 u32*)(u32)(uintptr_t)l, 16, 0, 0);
}

// v_permlane32_swap_b32: swaps a[32+i] <-> b[i]. After:
//   a'[lo l] = a[l],    a'[hi l] = b[l-32]  (partner's b)
//   b'[lo l] = a[l+32] (partner's a), b'[hi l] = b[l]
__device__ __forceinline__ void plswap(u32& a, u32& b) {
  u32x2 r = __builtin_amdgcn_permlane32_swap(a, b, false, false);
  a = r[0]; b = r[1];
}
// op(x, x from lane^32) on both halves, no select:
__device__ __forceinline__ float xmax32(float x) {
  u32 a = __builtin_bit_cast(u32, x), b = a;
  plswap(a, b);
  return fmaxf(__builtin_bit_cast(float, a), __builtin_bit_cast(float, b));
}
__device__ __forceinline__ float xsum32(float x) {
  u32 a = __builtin_bit_cast(u32, x), b = a;
  plswap(a, b);
  return __builtin_bit_cast(float, a) + __builtin_bit_cast(float, b);
}

// ---------------------------------------------------------------------------
// prep: x f32 -> bf16
// ---------------------------------------------------------------------------
__global__ __launch_bounds__(256) void msa_cvt_x(const float* __restrict__ x,
                                                 bf16_t* __restrict__ xb, int n4) {
  int i = blockIdx.x * 256 + threadIdx.x;
  if (i < n4) {
    const float4 v = ((const float4*)x)[i];
    bf16x4 o;
    o[0] = (bf16_t)v.x; o[1] = (bf16_t)v.y; o[2] = (bf16_t)v.z; o[3] = (bf16_t)v.w;
    ((bf16x4*)xb)[i] = o;
  }
}

// ---------------------------------------------------------------------------
// prep: weight transpose+convert: w[k][n] f32 -> wt[n][k] bf16
// ---------------------------------------------------------------------------
__global__ __launch_bounds__(256) void msa_transpose_w(
    const float* __restrict__ wq, const float* __restrict__ wk,
    const float* __restrict__ wv, const float* __restrict__ wo,
    bf16_t* __restrict__ wt_qkv, bf16_t* __restrict__ wt_o) {
  __shared__ float tile[32][33];
  const int a = blockIdx.z;
  const float* src = (a == 0) ? wq : (a == 1) ? wk : (a == 2) ? wv : wo;
  bf16_t* dst = (a < 3) ? (wt_qkv + (size_t)a * C_DIM * C_DIM) : wt_o;
  const int tx = threadIdx.x & 31, ty = threadIdx.x >> 5;
  const int bi = blockIdx.y * 32, bj = blockIdx.x * 32;
#pragma unroll
  for (int p = 0; p < 4; p++) {
    int r = p * 8 + ty;
    tile[r][tx] = src[(size_t)(bi + r) * C_DIM + bj + tx];
  }
  __syncthreads();
#pragma unroll
  for (int p = 0; p < 4; p++) {
    int r = p * 8 + ty;
    dst[(size_t)(bj + r) * C_DIM + bi + tx] = (bf16_t)tile[tx][r];
  }
}

// ---------------------------------------------------------------------------
// QKV GEMM, m97 structure
// ---------------------------------------------------------------------------
__global__ __launch_bounds__(256) void msa_gemm_qkv(
    const bf16_t* __restrict__ xb, const bf16_t* __restrict__ wt,
    const float* __restrict__ bq, const float* __restrict__ bk,
    const float* __restrict__ bv,
    bf16_t* __restrict__ qo, bf16_t* __restrict__ ko, bf16_t* __restrict__ vto) {
  __shared__ bf16_t lA[128 * 32];
  __shared__ bf16_t lB[128 * 32];
  const int tid = threadIdx.x;
  const int w = tid >> 6, lane = tid & 63;
  const int lr = lane & 15, lg = lane >> 4;
  const int m0 = blockIdx.y * 128;
  const int n0 = blockIdx.x * 128;
  const int wm = (w >> 1) * 64, wn = (w & 1) * 64;

  const int srow = tid >> 2, scol = (tid & 3) * 8;
  const bf16_t* ga = xb + (size_t)(m0 + srow) * C_DIM + scol;
  const bf16_t* gb = wt + (size_t)(n0 + srow) * C_DIM + scol;

  f32x4 acc[4][4];
#pragma unroll
  for (int i = 0; i < 4; i++)
#pragma unroll
    for (int j = 0; j < 4; j++) acc[i][j] = (f32x4){0.f, 0.f, 0.f, 0.f};

  for (int k0 = 0; k0 < C_DIM; k0 += 32) {
    gld_lds16(ga + k0, &lA[tid * 8]);
    gld_lds16(ga + (size_t)64 * C_DIM + k0, &lA[2048 + tid * 8]);
    gld_lds16(gb + k0, &lB[tid * 8]);
    gld_lds16(gb + (size_t)64 * C_DIM + k0, &lB[2048 + tid * 8]);
    __syncthreads();
    bf16x8 a[4], b[4];
#pragma unroll
    for (int mb = 0; mb < 4; mb++)
      a[mb] = *(const bf16x8*)&lA[(wm + mb * 16 + lr) * 32 + lg * 8];
#pragma unroll
    for (int nb = 0; nb < 4; nb++)
      b[nb] = *(const bf16x8*)&lB[(wn + nb * 16 + lr) * 32 + lg * 8];
#pragma unroll
    for (int mb = 0; mb < 4; mb++)
#pragma unroll
      for (int nb = 0; nb < 4; nb++)
        acc[mb][nb] = __builtin_amdgcn_mfma_f32_16x16x32_bf16(a[mb], b[nb], acc[mb][nb], 0, 0, 0);
    __syncthreads();
  }

#pragma unroll
  for (int nb = 0; nb < 4; nb++) {
    const int n = n0 + wn + nb * 16 + lr;
    const int g = n >> 10, c = n & 1023, h = c >> 6, d = c & 63;
    const float bias = (g == 0) ? bq[c] : (g == 1) ? bk[c] : bv[c];
#pragma unroll
    for (int mb = 0; mb < 4; mb++) {
#pragma unroll
      for (int r = 0; r < 4; r++) {
        const int m = m0 + wm + mb * 16 + lg * 4 + r;
        const int bi = m >> 11, t = m & (T_SEQ - 1);
        float v = acc[mb][nb][r] + bias;
        if (g == 0)
          qo[(((size_t)bi * NH + h) * T_SEQ + t) * DH + d] = (bf16_t)(v * Q_SCALE);
        else if (g == 1)
          ko[(((size_t)bi * NH + h) * T_SEQ + t) * DH + d] = (bf16_t)v;
        else
          vto[(((size_t)bi * NH + h) * DH + d) * T_SEQ + t] = (bf16_t)v;
      }
    }
  }
}

// ---------------------------------------------------------------------------
// attn softmax + pack (permlane32_swap version: no LDS, no selects)
// ---------------------------------------------------------------------------
__device__ __forceinline__ void sm_pack(f32x16& s, float& m_run, float& l_run,
                                        f32x16& o0, f32x16& o1,
                                        bf16x8& pa0, bf16x8& pa1) {
  // max tree shaped for v_max3 fusion
  float t0 = fmaxf(fmaxf(s[0], s[1]), s[2]);
  float t1 = fmaxf(fmaxf(s[3], s[4]), s[5]);
  float t2 = fmaxf(fmaxf(s[6], s[7]), s[8]);
  float t3 = fmaxf(fmaxf(s[9], s[10]), s[11]);
  float t4 = fmaxf(fmaxf(s[12], s[13]), s[14]);
  float t5 = fmaxf(fmaxf(t0, t1), s[15]);
  float mt = fmaxf(fmaxf(fmaxf(t2, t3), t4), t5);
  mt = xmax32(mt);

  if (__any(mt > m_run + DEFER_THR)) {
    const float mnew = fmaxf(m_run, mt);
    const float al = __builtin_amdgcn_exp2f(m_run - mnew);
    m_run = mnew;
    l_run *= al;
#pragma unroll
    for (int r = 0; r < 16; r++) { o0[r] *= al; o1[r] *= al; }
  }

#pragma unroll
  for (int r = 0; r < 16; r++) s[r] = __builtin_amdgcn_exp2f(s[r] - m_run);
  {
    float a0 = (s[0] + s[1]) + (s[2] + s[3]);
    float a1 = (s[4] + s[5]) + (s[6] + s[7]);
    float a2 = (s[8] + s[9]) + (s[10] + s[11]);
    float a3 = (s[12] + s[13]) + (s[14] + s[15]);
    l_run += xsum32((a0 + a1) + (a2 + a3));
  }

  // pack to bf16 pairs, then 4 permlane32_swap produce both fragment words
  // each (verified against the R4 select network), no cndmasks:
  u32 pk8[8];
#pragma unroll
  for (int i = 0; i < 8; i++) {
    const unsigned short lo = __builtin_bit_cast(unsigned short, (bf16_t)s[2 * i]);
    const unsigned short hh = __builtin_bit_cast(unsigned short, (bf16_t)s[2 * i + 1]);
    pk8[i] = ((u32)hh << 16) | (u32)lo;
  }
  u32 f0w0 = pk8[0], f0w2 = pk8[2];
  u32 f0w1 = pk8[1], f0w3 = pk8[3];
  u32 f1w0 = pk8[4], f1w2 = pk8[6];
  u32 f1w1 = pk8[5], f1w3 = pk8[7];
  plswap(f0w0, f0w2);
  plswap(f0w1, f0w3);
  plswap(f1w0, f1w2);
  plswap(f1w1, f1w3);
  const u32x4 q0v = {f0w0, f0w1, f0w2, f0w3};
  const u32x4 q1v = {f1w0, f1w1, f1w2, f1w3};
  pa0 = __builtin_bit_cast(bf16x8, q0v);
  pa1 = __builtin_bit_cast(bf16x8, q1v);
}

__device__ __forceinline__ void store_o(f32x16& o0, f32x16& o1, float l_fin,
                                        bf16_t* __restrict__ orow, const int hi) {
  const float inv = 1.0f / l_fin;
#pragma unroll
  for (int db = 0; db < 2; db++) {
#pragma unroll
    for (int r = 0; r < 16; r += 2) {
      const int d = db * 32 + (r & 3) + 8 * (r >> 2) + 4 * hi;
      const float v0 = (db ? o1[r] : o0[r]) * inv;
      const float v1 = (db ? o1[r + 1] : o0[r + 1]) * inv;
      const unsigned short b0 = __builtin_bit_cast(unsigned short, (bf16_t)v0);
      const unsigned short b1 = __builtin_bit_cast(unsigned short, (bf16_t)v1);
      *reinterpret_cast<u32*>(orow + d) = ((u32)b1 << 16) | (u32)b0;
    }
  }
}

// ---------------------------------------------------------------------------
// Flash attention (causal): dual-stream pairs + K-split-2.
// Grid (bh=64, pair=32), block 128 = 2 waves. Wave s handles kt ≡ s (mod 2)
// for BOTH streams of the pair (tL=63-p, tS=p): perfect balance (~32.5
// iters/wave), K/V tiles still shared between streams, 2x the waves in
// flight vs R4. Partials merged via online-softmax combining in LDS.
// ---------------------------------------------------------------------------
__global__ __launch_bounds__(128, 2) void msa_attn32(
    const bf16_t* __restrict__ Q, const bf16_t* __restrict__ K,
    const bf16_t* __restrict__ Vt, bf16_t* __restrict__ O) {
  __shared__ float mlb[2][2][2][32];   // [wave][stream][m|l][q-row]
  __shared__ float ob[2][2][16][64];   // [wave][accIdx][reg][lane]
  const int tid = threadIdx.x;
  const int w = tid >> 6;
  const int lane = tid & 63;
  const int l31 = lane & 31;
  const int hi = lane >> 5;
  const int bh = blockIdx.x;
  const int p = blockIdx.y;
  const int tS = p, tL = 63 - p;
  const int q0S = tS * 32, q0L = tL * 32;

  const bf16_t* Qh = Q + (size_t)bh * T_SEQ * DH;
  const bf16_t* Kh = K + (size_t)bh * T_SEQ * DH;
  const bf16_t* Vh = Vt + (size_t)bh * DH * T_SEQ;

  bf16x8 qfL[4], qfS[4];
#pragma unroll
  for (int dc = 0; dc < 4; dc++) {
    qfL[dc] = *(const bf16x8*)(Qh + (size_t)(q0L + l31) * DH + dc * 16 + hi * 8);
    qfS[dc] = *(const bf16x8*)(Qh + (size_t)(q0S + l31) * DH + dc * 16 + hi * 8);
  }

  f32x16 oL0, oL1, oS0, oS1;
#pragma unroll
  for (int r = 0; r < 16; r++) { oL0[r] = 0.f; oL1[r] = 0.f; oS0[r] = 0.f; oS1[r] = 0.f; }
  float mL = -1e30f, lL = 0.f, mS = -1e30f, lS = 0.f;
  const f32x16 z16 = {};  // shared zero C-operand: no per-iter acc zeroing

  int kt = w;  // this wave's K-tiles: w, w+2, w+4, ...
  bf16x8 kfA[4], kfB[4];
#pragma unroll
  for (int dc = 0; dc < 4; dc++)
    kfA[dc] = *(const bf16x8*)(Kh + (size_t)(kt * 32 + l31) * DH + dc * 16 + hi * 8);

#define ATTN_BODY(KC, KN)                                                          \
  {                                                                                \
    const int j0 = kt * 32;                                                        \
    const int jn = (kt + 2 <= tL) ? (kt + 2) * 32 : 0;                             \
    _Pragma("unroll") for (int dc = 0; dc < 4; dc++)                               \
        KN[dc] = *(const bf16x8*)(Kh + (size_t)(jn + l31) * DH + dc * 16 + hi * 8);\
    const bf16x8 vf00 = *(const bf16x8*)(Vh + (size_t)l31 * T_SEQ + j0 + hi * 8);  \
    const bf16x8 vf01 = *(const bf16x8*)(Vh + (size_t)l31 * T_SEQ + j0 + 16 + hi * 8); \
    const bf16x8 vf10 = *(const bf16x8*)(Vh + (size_t)(32 + l31) * T_SEQ + j0 + hi * 8); \
    const bf16x8 vf11 = *(const bf16x8*)(Vh + (size_t)(32 + l31) * T_SEQ + j0 + 16 + hi * 8); \
    const bool actS = (kt <= tS);                                                  \
    f32x16 sL = __builtin_amdgcn_mfma_f32_32x32x16_bf16(KC[0], qfL[0], z16, 0, 0, 0); \
    _Pragma("unroll") for (int dc = 1; dc < 4; dc++)                               \
        sL = __builtin_amdgcn_mfma_f32_32x32x16_bf16(KC[dc], qfL[dc], sL, 0, 0, 0);\
    f32x16 sS;                                                                     \
    if (actS) {                                                                    \
      sS = __builtin_amdgcn_mfma_f32_32x32x16_bf16(KC[0], qfS[0], z16, 0, 0, 0);   \
      _Pragma("unroll") for (int dc = 1; dc < 4; dc++)                             \
          sS = __builtin_amdgcn_mfma_f32_32x32x16_bf16(KC[dc], qfS[dc], sS, 0, 0, 0); \
    }                                                                              \
    if (kt == tL) {                                                                \
      _Pragma("unroll") for (int r = 0; r < 16; r++) {                             \
        const int jrow = (r & 3) + 8 * (r >> 2) + 4 * hi;                          \
        if (jrow > l31) sL[r] = -1e30f;                                            \
      }                                                                            \
    }                                                                              \
    if (kt == tS) {                                                                \
      _Pragma("unroll") for (int r = 0; r < 16; r++) {                             \
        const int jrow = (r & 3) + 8 * (r >> 2) + 4 * hi;                          \
        if (jrow > l31) sS[r] = -1e30f;                                            \
      }                                                                            \
    }                                                                              \
    bf16x8 paL0, paL1;                                                             \
    sm_pack(sL, mL, lL, oL0, oL1, paL0, paL1);                                     \
    oL0 = __builtin_amdgcn_mfma_f32_32x32x16_bf16(vf00, paL0, oL0, 0, 0, 0);       \
    oL1 = __builtin_amdgcn_mfma_f32_32x32x16_bf16(vf10, paL0, oL1, 0, 0, 0);       \
    oL0 = __builtin_amdgcn_mfma_f32_32x32x16_bf16(vf01, paL1, oL0, 0, 0, 0);       \
    oL1 = __builtin_amdgcn_mfma_f32_32x32x16_bf16(vf11, paL1, oL1, 0, 0, 0);       \
    if (actS) {                                                                    \
      bf16x8 paS0, paS1;                                                           \
      sm_pack(sS, mS, lS, oS0, oS1, paS0, paS1);                                   \
      oS0 = __builtin_amdgcn_mfma_f32_32x32x16_bf16(vf00, paS0, oS0, 0, 0, 0);     \
      oS1 = __builtin_amdgcn_mfma_f32_32x32x16_bf16(vf10, paS0, oS1, 0, 0, 0);     \
      oS0 = __builtin_amdgcn_mfma_f32_32x32x16_bf16(vf01, paS1, oS0, 0, 0, 0);     \
      oS1 = __builtin_amdgcn_mfma_f32_32x32x16_bf16(vf11, paS1, oS1, 0, 0, 0);     \
    }                                                                              \
  }

  while (kt <= tL) {
    ATTN_BODY(kfA, kfB);
    kt += 2;
    if (kt > tL) break;
    ATTN_BODY(kfB, kfA);
    kt += 2;
  }
#undef ATTN_BODY

  // ---- merge the two K-halves (online-softmax combining) ----
  if (hi == 0) {
    mlb[w][0][0][l31] = mL; mlb[w][0][1][l31] = lL;
    mlb[w][1][0][l31] = mS; mlb[w][1][1][l31] = lS;
  }
  __syncthreads();
  const int ow = w ^ 1;
  const float mLo = mlb[ow][0][0][l31], lLo = mlb[ow][0][1][l31];
  const float mSo = mlb[ow][1][0][l31], lSo = mlb[ow][1][1][l31];

  const float ML = fmaxf(mL, mLo);
  const float scL = __builtin_amdgcn_exp2f(mL - ML);
  const float lLf = lL * scL + lLo * __builtin_amdgcn_exp2f(mLo - ML);
  const float MS = fmaxf(mS, mSo);
  const float scS = __builtin_amdgcn_exp2f(mS - MS);
  const float lSf = lS * scS + lSo * __builtin_amdgcn_exp2f(mSo - MS);

  // wave 0 stores stream L, so it publishes its S partial (scaled); vice versa.
  if (w == 0) {
#pragma unroll
    for (int r = 0; r < 16; r++) {
      ob[0][0][r][lane] = oS0[r] * scS;
      ob[0][1][r][lane] = oS1[r] * scS;
    }
  } else {
#pragma unroll
    for (int r = 0; r < 16; r++) {
      ob[1][0][r][lane] = oL0[r] * scL;
      ob[1][1][r][lane] = oL1[r] * scL;
    }
  }
  __syncthreads();

  const int b = bh >> 4, h = bh & 15;
  if (w == 0) {
#pragma unroll
    for (int r = 0; r < 16; r++) {
      oL0[r] = oL0[r] * scL + ob[1][0][r][lane];
      oL1[r] = oL1[r] * scL + ob[1][1][r][lane];
    }
    store_o(oL0, oL1, lLf, O + ((size_t)b * T_SEQ + q0L + l31) * C_DIM + h * DH, hi);
  } else {
#pragma unroll
    for (int r = 0; r < 16; r++) {
      oS0[r] = oS0[r] * scS + ob[0][0][r][lane];
      oS1[r] = oS1[r] * scS + ob[0][1][r][lane];
    }
    store_o(oS0, oS1, lSf, O + ((size_t)b * T_SEQ + q0S + l31) * C_DIM + h * DH, hi);
  }
}

// ---------------------------------------------------------------------------
// Output projection, m97 structure
// ---------------------------------------------------------------------------
__global__ __launch_bounds__(256) void msa_gemm_out(
    const bf16_t* __restrict__ ab, const bf16_t* __restrict__ wt,
    const float* __restrict__ bo, float* __restrict__ out) {
  __shared__ bf16_t lA[128 * 32];
  __shared__ bf16_t lB[128 * 32];
  const int tid = threadIdx.x;
  const int w = tid >> 6, lane = tid & 63;
  const int lr = lane & 15, lg = lane >> 4;
  const int m0 = blockIdx.y * 128;
  const int n0 = blockIdx.x * 128;
  const int wm = (w >> 1) * 64, wn = (w & 1) * 64;

  const int srow = tid >> 2, scol = (tid & 3) * 8;
  const bf16_t* ga = ab + (size_t)(m0 + srow) * C_DIM + scol;
  const bf16_t* gb = wt + (size_t)(n0 + srow) * C_DIM + scol;

  f32x4 acc[4][4];
#pragma unroll
  for (int i = 0; i < 4; i++)
#pragma unroll
    for (int j = 0; j < 4; j++) acc[i][j] = (f32x4){0.f, 0.f, 0.f, 0.f};

  for (int k0 = 0; k0 < C_DIM; k0 += 32) {
    gld_lds16(ga + k0, &lA[tid * 8]);
    gld_lds16(ga + (size_t)64 * C_DIM + k0, &lA[2048 + tid * 8]);
    gld_lds16(gb + k0, &lB[tid * 8]);
    gld_lds16(gb + (size_t)64 * C_DIM + k0, &lB[2048 + tid * 8]);
    __syncthreads();
    bf16x8 a[4], b[4];
#pragma unroll
    for (int mb = 0; mb < 4; mb++)
      a[mb] = *(const bf16x8*)&lA[(wm + mb * 16 + lr) * 32 + lg * 8];
#pragma unroll
    for (int nb = 0; nb < 4; nb++)
      b[nb] = *(const bf16x8*)&lB[(wn + nb * 16 + lr) * 32 + lg * 8];
#pragma unroll
    for (int mb = 0; mb < 4; mb++)
#pragma unroll
      for (int nb = 0; nb < 4; nb++)
        acc[mb][nb] = __builtin_amdgcn_mfma_f32_16x16x32_bf16(a[mb], b[nb], acc[mb][nb], 0, 0, 0);
    __syncthreads();
  }

#pragma unroll
  for (int nb = 0; nb < 4; nb++) {
    const int n = n0 + wn + nb * 16 + lr;
    const float bias = bo[n];
#pragma unroll
    for (int mb = 0; mb < 4; mb++) {
#pragma unroll
      for (int r = 0; r < 4; r++) {
        const int m = m0 + wm + mb * 16 + lg * 4 + r;
        out[(size_t)m * C_DIM + n] = acc[mb][nb][r] + bias;
      }
    }
  }
}

// ---------------------------------------------------------------------------
// launch
// ---------------------------------------------------------------------------
extern "C" void kernel_launch(void* const* d_in, const int* in_sizes, int n_in,
                              void* d_out, int out_size, void* d_ws, size_t ws_size,
                              hipStream_t stream) {
  const float* x  = (const float*)d_in[0];
  const float* wq = (const float*)d_in[2];
  const float* bq = (const float*)d_in[3];
  const float* wk = (const float*)d_in[4];
  const float* bk = (const float*)d_in[5];
  const float* wv = (const float*)d_in[6];
  const float* bv = (const float*)d_in[7];
  const float* wo = (const float*)d_in[8];
  const float* bo = (const float*)d_in[9];

  char* ws = (char*)d_ws;
  bf16_t* xb     = (bf16_t*)(ws);
  bf16_t* wt_qkv = (bf16_t*)(ws + (16ull << 20));
  bf16_t* wt_o   = (bf16_t*)(ws + (22ull << 20));
  bf16_t* qb     = (bf16_t*)(ws + (24ull << 20));
  bf16_t* kb     = (bf16_t*)(ws + (40ull << 20));
  bf16_t* vtb    = (bf16_t*)(ws + (56ull << 20));
  bf16_t* attn_o = xb;  // alias: xb dead after QKV GEMM

  const int n4 = M_TOK * C_DIM / 4;
  msa_cvt_x<<<n4 / 256, 256, 0, stream>>>(x, xb, n4);
  msa_transpose_w<<<dim3(32, 32, 4), 256, 0, stream>>>(wq, wk, wv, wo, wt_qkv, wt_o);
  msa_gemm_qkv<<<dim3(24, 64), 256, 0, stream>>>(xb, wt_qkv, bq, bk, bv, qb, kb, vtb);
  msa_attn32<<<dim3(64, 32), 128, 0, stream>>>(qb, kb, vtb, attn_o);
  msa_gemm_out<<<dim3(8, 64), 256, 0, stream>>>(attn_o, wt_o, bo, (float*)d_out);
}